// Round 2
// baseline (2049.489 us; speedup 1.0000x reference)
//
#include <hip/hip_runtime.h>

#define N_NODES  100000
#define N_EDGES  1600000
#define D_FEAT   64
#define N_GRAPHS 1000
#define D_MSG    30
#define D_H1     20
#define D_H2     10
#define P_STRIDE 64   // P row: [0..29]=P0 (src proj + bias), [32..61]=P1 (dst proj)

// ---------------------------------------------------------------------------
// K0: per-node projections  P0[n] = x[n]@W0 + b_msg,  P1[n] = x[n]@W1
// (W0 = W_msg rows 0..63, W1 = rows 64..127). Amortizes node work over ~16
// edges/node: edge kernel then only needs the e_attr @ W2 part.
// ---------------------------------------------------------------------------
__global__ __launch_bounds__(256, 4) void node_proj_kernel(
    const float* __restrict__ node_attr,   // [N_NODES][64]
    const float* __restrict__ W_msg,       // [192][30]
    const float* __restrict__ b_msg,       // [30]
    float*       __restrict__ P)           // [N_NODES][P_STRIDE]
{
    const int n = blockIdx.x * 256 + threadIdx.x;
    if (n >= N_NODES) return;

    float a0[D_MSG], a1[D_MSG];
#pragma unroll
    for (int j = 0; j < D_MSG; ++j) { a0[j] = b_msg[j]; a1[j] = 0.0f; }

    const float4* px = (const float4*)(node_attr + (size_t)n * D_FEAT);
#pragma unroll
    for (int q = 0; q < 16; ++q) {
        const float4 v  = px[q];
        const float* w0 = W_msg + (q * 4) * D_MSG;            // src block rows
        const float* w1 = W_msg + (D_FEAT + q * 4) * D_MSG;   // dst block rows
#pragma unroll
        for (int j = 0; j < D_MSG; ++j) a0[j] = fmaf(v.x, w0[j],           a0[j]);
#pragma unroll
        for (int j = 0; j < D_MSG; ++j) a0[j] = fmaf(v.y, w0[D_MSG + j],   a0[j]);
#pragma unroll
        for (int j = 0; j < D_MSG; ++j) a0[j] = fmaf(v.z, w0[2*D_MSG + j], a0[j]);
#pragma unroll
        for (int j = 0; j < D_MSG; ++j) a0[j] = fmaf(v.w, w0[3*D_MSG + j], a0[j]);
#pragma unroll
        for (int j = 0; j < D_MSG; ++j) a1[j] = fmaf(v.x, w1[j],           a1[j]);
#pragma unroll
        for (int j = 0; j < D_MSG; ++j) a1[j] = fmaf(v.y, w1[D_MSG + j],   a1[j]);
#pragma unroll
        for (int j = 0; j < D_MSG; ++j) a1[j] = fmaf(v.z, w1[2*D_MSG + j], a1[j]);
#pragma unroll
        for (int j = 0; j < D_MSG; ++j) a1[j] = fmaf(v.w, w1[3*D_MSG + j], a1[j]);
    }

    float* pr = P + (size_t)n * P_STRIDE;
#pragma unroll
    for (int j = 0; j < D_MSG; ++j) pr[j]      = a0[j];
    pr[30] = 0.0f; pr[31] = 0.0f;                 // pad so edge kernel can float4-load
#pragma unroll
    for (int j = 0; j < D_MSG; ++j) pr[32 + j] = a1[j];
    pr[62] = 0.0f; pr[63] = 0.0f;
}

// ---------------------------------------------------------------------------
// K1: per-edge  msg = relu(P0[src] + P1[dst] + e_attr @ W2);  x[dst] += msg
// ---------------------------------------------------------------------------
__global__ __launch_bounds__(256, 4) void edge_msg_kernel(
    const int*   __restrict__ edge_index,  // [2][N_EDGES]
    const float* __restrict__ P,           // [N_NODES][P_STRIDE]
    const float* __restrict__ edge_attr,   // [N_EDGES][64]
    const float* __restrict__ W_msg,       // [192][30]
    float*       __restrict__ x)           // [N_NODES][30] (pre-zeroed)
{
    const int e = blockIdx.x * 256 + threadIdx.x;
    const int s = edge_index[e];
    const int d = edge_index[N_EDGES + e];

    const float4* p0 = (const float4*)(P + (size_t)s * P_STRIDE);
    const float4* p1 = (const float4*)(P + (size_t)d * P_STRIDE + 32);

    float acc[32];
#pragma unroll
    for (int q = 0; q < 8; ++q) {
        const float4 u = p0[q];
        const float4 w = p1[q];
        acc[4*q + 0] = u.x + w.x;
        acc[4*q + 1] = u.y + w.y;
        acc[4*q + 2] = u.z + w.z;
        acc[4*q + 3] = u.w + w.w;
    }

    const float* W2 = W_msg + 2 * D_FEAT * D_MSG;   // rows 128..191
    const float4* pe = (const float4*)(edge_attr + (size_t)e * D_FEAT);
#pragma unroll
    for (int q = 0; q < 16; ++q) {
        const float4 v  = pe[q];
        const float* wr = W2 + q * 4 * D_MSG;
#pragma unroll
        for (int j = 0; j < D_MSG; ++j) acc[j] = fmaf(v.x, wr[j],           acc[j]);
#pragma unroll
        for (int j = 0; j < D_MSG; ++j) acc[j] = fmaf(v.y, wr[D_MSG + j],   acc[j]);
#pragma unroll
        for (int j = 0; j < D_MSG; ++j) acc[j] = fmaf(v.z, wr[2*D_MSG + j], acc[j]);
#pragma unroll
        for (int j = 0; j < D_MSG; ++j) acc[j] = fmaf(v.w, wr[3*D_MSG + j], acc[j]);
    }

    float* xr = x + (size_t)d * D_MSG;
#pragma unroll
    for (int j = 0; j < D_MSG; ++j) {
        const float m = fmaxf(acc[j], 0.0f);
        if (m > 0.0f) atomicAdd(xr + j, m);   // skip zero contributions
    }
}

// ---------------------------------------------------------------------------
// K2: per-node head  h = relu(x @ W1 + b1), pooled into graph accumulator.
// ---------------------------------------------------------------------------
__global__ __launch_bounds__(256) void node_head_kernel(
    const float* __restrict__ x,       // [N_NODES][30]
    const int*   __restrict__ batch,   // [N_NODES]
    const float* __restrict__ W1,      // [30][20]
    const float* __restrict__ b1,      // [20]
    float*       __restrict__ g)       // [N_GRAPHS][20] (pre-zeroed)
{
    const int n = blockIdx.x * 256 + threadIdx.x;
    if (n >= N_NODES) return;

    float xv[D_MSG];
    const float2* px = (const float2*)(x + (size_t)n * D_MSG);
#pragma unroll
    for (int j = 0; j < D_MSG / 2; ++j) {
        const float2 t = px[j];
        xv[2*j] = t.x; xv[2*j+1] = t.y;
    }

    float h[D_H1];
#pragma unroll
    for (int t = 0; t < D_H1; ++t) h[t] = b1[t];
#pragma unroll
    for (int j = 0; j < D_MSG; ++j) {
#pragma unroll
        for (int t = 0; t < D_H1; ++t) h[t] = fmaf(xv[j], W1[j * D_H1 + t], h[t]);
    }

    const int gi = batch[n];
    float* gr = g + (size_t)gi * D_H1;
#pragma unroll
    for (int t = 0; t < D_H1; ++t) {
        const float hv = fmaxf(h[t], 0.0f);
        if (hv > 0.0f) atomicAdd(gr + t, hv);
    }
}

// ---------------------------------------------------------------------------
// K3: per-graph head  out = relu(g @ W2 + b2) @ W3 + b3
// ---------------------------------------------------------------------------
__global__ __launch_bounds__(256) void graph_head_kernel(
    const float* __restrict__ g,    // [N_GRAPHS][20]
    const float* __restrict__ W2,   // [20][10]
    const float* __restrict__ b2,   // [10]
    const float* __restrict__ W3,   // [10][1]
    const float* __restrict__ b3,   // [1]
    float*       __restrict__ out)  // [N_GRAPHS]
{
    const int i = blockIdx.x * 256 + threadIdx.x;
    if (i >= N_GRAPHS) return;

    float gv[D_H1];
    const float2* pg = (const float2*)(g + (size_t)i * D_H1);
#pragma unroll
    for (int j = 0; j < D_H1 / 2; ++j) {
        const float2 t = pg[j];
        gv[2*j] = t.x; gv[2*j+1] = t.y;
    }

    float h[D_H2];
#pragma unroll
    for (int t = 0; t < D_H2; ++t) h[t] = b2[t];
#pragma unroll
    for (int j = 0; j < D_H1; ++j) {
#pragma unroll
        for (int t = 0; t < D_H2; ++t) h[t] = fmaf(gv[j], W2[j * D_H2 + t], h[t]);
    }

    float o = b3[0];
#pragma unroll
    for (int t = 0; t < D_H2; ++t) o = fmaf(fmaxf(h[t], 0.0f), W3[t], o);

    out[i] = o;
}

// ---------------------------------------------------------------------------
extern "C" void kernel_launch(void* const* d_in, const int* in_sizes, int n_in,
                              void* d_out, int out_size, void* d_ws, size_t ws_size,
                              hipStream_t stream)
{
    const int*   edge_index = (const int*)  d_in[0];
    const float* node_attr  = (const float*)d_in[1];
    const float* edge_attr  = (const float*)d_in[2];
    const int*   batch      = (const int*)  d_in[3];
    const float* W_msg      = (const float*)d_in[4];
    const float* b_msg      = (const float*)d_in[5];
    const float* W1         = (const float*)d_in[6];
    const float* b1         = (const float*)d_in[7];
    const float* W2         = (const float*)d_in[8];
    const float* b2         = (const float*)d_in[9];
    const float* W3         = (const float*)d_in[10];
    const float* b3         = (const float*)d_in[11];

    float* x = (float*)d_ws;                               // [N_NODES][30]
    float* g = x + (size_t)N_NODES * D_MSG;                // [N_GRAPHS][20]
    float* P = g + (size_t)N_GRAPHS * D_H1;                // [N_NODES][64] (16B-aligned)

    const size_t zero_bytes =
        ((size_t)N_NODES * D_MSG + (size_t)N_GRAPHS * D_H1) * sizeof(float);
    hipMemsetAsync(d_ws, 0, zero_bytes, stream);

    node_proj_kernel<<<(N_NODES + 255) / 256, 256, 0, stream>>>(
        node_attr, W_msg, b_msg, P);

    edge_msg_kernel<<<N_EDGES / 256, 256, 0, stream>>>(
        edge_index, P, edge_attr, W_msg, x);

    node_head_kernel<<<(N_NODES + 255) / 256, 256, 0, stream>>>(
        x, batch, W1, b1, g);

    graph_head_kernel<<<(N_GRAPHS + 255) / 256, 256, 0, stream>>>(
        g, W2, b2, W3, b3, (float*)d_out);
}

// Round 3
// 606.517 us; speedup vs baseline: 3.3791x; 3.3791x over previous
//
#include <hip/hip_runtime.h>

#define N_NODES    100000
#define N_EDGES    1600000
#define D_FEAT     64
#define N_GRAPHS   1000
#define D_MSG      30
#define D_H1       20
#define D_H2       10
#define P_STRIDE   64     // P row: [0..29]=P0(src proj+bias), pad, [32..61]=P1(dst proj), pad
#define MSG_STRIDE 32     // 128B-aligned message rows
#define N_SCAN     (N_NODES + 1)
#define N_SCAN_PAD 100004
#define NB_SCAN    ((N_SCAN + 1023) / 1024)   // 98

// ---------------------------------------------------------------------------
// K0: per-node projections  P0[n] = x[n]@W0 + b_msg,  P1[n] = x[n]@W1
// ---------------------------------------------------------------------------
__global__ __launch_bounds__(256) void node_proj_kernel(
    const float* __restrict__ node_attr,   // [N_NODES][64]
    const float* __restrict__ W_msg,       // [192][30]
    const float* __restrict__ b_msg,       // [30]
    float*       __restrict__ P)           // [N_NODES][P_STRIDE]
{
    const int n = blockIdx.x * 256 + threadIdx.x;
    if (n >= N_NODES) return;

    float a0[D_MSG], a1[D_MSG];
#pragma unroll
    for (int j = 0; j < D_MSG; ++j) { a0[j] = b_msg[j]; a1[j] = 0.0f; }

    const float4* px = (const float4*)(node_attr + (size_t)n * D_FEAT);
#pragma unroll 2
    for (int q = 0; q < 16; ++q) {
        const float4 v  = px[q];
        const float* w0 = W_msg + (q * 4) * D_MSG;
        const float* w1 = W_msg + (D_FEAT + q * 4) * D_MSG;
#pragma unroll
        for (int j = 0; j < D_MSG; ++j) a0[j] = fmaf(v.x, w0[j],           a0[j]);
#pragma unroll
        for (int j = 0; j < D_MSG; ++j) a0[j] = fmaf(v.y, w0[D_MSG + j],   a0[j]);
#pragma unroll
        for (int j = 0; j < D_MSG; ++j) a0[j] = fmaf(v.z, w0[2*D_MSG + j], a0[j]);
#pragma unroll
        for (int j = 0; j < D_MSG; ++j) a0[j] = fmaf(v.w, w0[3*D_MSG + j], a0[j]);
#pragma unroll
        for (int j = 0; j < D_MSG; ++j) a1[j] = fmaf(v.x, w1[j],           a1[j]);
#pragma unroll
        for (int j = 0; j < D_MSG; ++j) a1[j] = fmaf(v.y, w1[D_MSG + j],   a1[j]);
#pragma unroll
        for (int j = 0; j < D_MSG; ++j) a1[j] = fmaf(v.z, w1[2*D_MSG + j], a1[j]);
#pragma unroll
        for (int j = 0; j < D_MSG; ++j) a1[j] = fmaf(v.w, w1[3*D_MSG + j], a1[j]);
    }

    float4* pr = (float4*)(P + (size_t)n * P_STRIDE);
#pragma unroll
    for (int q = 0; q < 7; ++q)
        pr[q]     = make_float4(a0[4*q], a0[4*q+1], a0[4*q+2], a0[4*q+3]);
    pr[7]         = make_float4(a0[28], a0[29], 0.0f, 0.0f);
#pragma unroll
    for (int q = 0; q < 7; ++q)
        pr[8 + q] = make_float4(a1[4*q], a1[4*q+1], a1[4*q+2], a1[4*q+3]);
    pr[15]        = make_float4(a1[28], a1[29], 0.0f, 0.0f);
}

// ---------------------------------------------------------------------------
// CSR build: histogram of dst, 2-level exclusive scan, cursor init.
// ---------------------------------------------------------------------------
__global__ __launch_bounds__(256) void hist_kernel(
    const int* __restrict__ edge_index, int* __restrict__ cnt)
{
    const int e = blockIdx.x * 256 + threadIdx.x;
    atomicAdd(&cnt[edge_index[N_EDGES + e]], 1);
}

__global__ __launch_bounds__(1024) void scan_a(
    const int* __restrict__ cnt, int* __restrict__ offs, int* __restrict__ bsum)
{
    __shared__ int sh[1024];
    const int t = threadIdx.x;
    const int i = blockIdx.x * 1024 + t;
    const int v = (i < N_SCAN) ? cnt[i] : 0;
    sh[t] = v;
    __syncthreads();
#pragma unroll
    for (int off = 1; off < 1024; off <<= 1) {
        int u = 0;
        if (t >= off) u = sh[t - off];
        __syncthreads();
        if (t >= off) sh[t] += u;
        __syncthreads();
    }
    if (i < N_SCAN) offs[i] = sh[t] - v;            // block-local exclusive
    if (t == 1023) bsum[blockIdx.x] = sh[1023];     // block total
}

__global__ __launch_bounds__(128) void scan_b(int* __restrict__ bsum)
{
    __shared__ int sh[128];
    const int t = threadIdx.x;
    const int v = (t < NB_SCAN) ? bsum[t] : 0;
    sh[t] = v;
    __syncthreads();
#pragma unroll
    for (int off = 1; off < 128; off <<= 1) {
        int u = 0;
        if (t >= off) u = sh[t - off];
        __syncthreads();
        if (t >= off) sh[t] += u;
        __syncthreads();
    }
    if (t < NB_SCAN) bsum[t] = sh[t] - v;           // exclusive block bases
}

__global__ __launch_bounds__(1024) void scan_c(
    int* __restrict__ offs, const int* __restrict__ bsum, int* __restrict__ cur)
{
    const int i = blockIdx.x * 1024 + threadIdx.x;
    if (i < N_SCAN) {
        const int o = offs[i] + bsum[blockIdx.x];
        offs[i] = o;
        cur[i]  = o;
    }
}

// ---------------------------------------------------------------------------
// K4: per-edge msg = relu(P0[src]+P1[dst]+e_attr@W2), streamed to CSR slot.
// No fp32 atomics: one int atomic for the slot, one 120B streaming write.
// ---------------------------------------------------------------------------
__global__ __launch_bounds__(256, 4) void edge_msg_scatter(
    const int*   __restrict__ edge_index,
    const float* __restrict__ P,
    const float* __restrict__ edge_attr,
    const float* __restrict__ W_msg,
    int*         __restrict__ cur,
    float*       __restrict__ msg_s)       // [N_EDGES][MSG_STRIDE]
{
    const int e = blockIdx.x * 256 + threadIdx.x;
    const int s = edge_index[e];
    const int d = edge_index[N_EDGES + e];
    const int p = atomicAdd(&cur[d], 1);   // slot in d's segment (issued early)

    const float4* p0 = (const float4*)(P + (size_t)s * P_STRIDE);
    const float4* p1 = (const float4*)(P + (size_t)d * P_STRIDE + 32);

    float acc[D_MSG];
#pragma unroll
    for (int q = 0; q < 7; ++q) {
        const float4 u = p0[q], w = p1[q];
        acc[4*q+0] = u.x + w.x; acc[4*q+1] = u.y + w.y;
        acc[4*q+2] = u.z + w.z; acc[4*q+3] = u.w + w.w;
    }
    {
        const float2 u = ((const float2*)p0)[14], w = ((const float2*)p1)[14];
        acc[28] = u.x + w.x; acc[29] = u.y + w.y;
    }

    const float* W2 = W_msg + 2 * D_FEAT * D_MSG;
    const float4* pe = (const float4*)(edge_attr + (size_t)e * D_FEAT);
#pragma unroll 2
    for (int q = 0; q < 16; ++q) {
        const float4 v  = pe[q];
        const float* wr = W2 + q * 4 * D_MSG;
#pragma unroll
        for (int j = 0; j < D_MSG; ++j) acc[j] = fmaf(v.x, wr[j],           acc[j]);
#pragma unroll
        for (int j = 0; j < D_MSG; ++j) acc[j] = fmaf(v.y, wr[D_MSG + j],   acc[j]);
#pragma unroll
        for (int j = 0; j < D_MSG; ++j) acc[j] = fmaf(v.z, wr[2*D_MSG + j], acc[j]);
#pragma unroll
        for (int j = 0; j < D_MSG; ++j) acc[j] = fmaf(v.w, wr[3*D_MSG + j], acc[j]);
    }

#pragma unroll
    for (int j = 0; j < D_MSG; ++j) acc[j] = fmaxf(acc[j], 0.0f);

    float* mr = msg_s + (size_t)p * MSG_STRIDE;
#pragma unroll
    for (int q = 0; q < 7; ++q)
        ((float4*)mr)[q] = make_float4(acc[4*q], acc[4*q+1], acc[4*q+2], acc[4*q+3]);
    ((float2*)mr)[14] = make_float2(acc[28], acc[29]);
}

// ---------------------------------------------------------------------------
// K5: per-node segment sum (contiguous CSR rows) + 30->20 head + graph pool.
// ---------------------------------------------------------------------------
__global__ __launch_bounds__(256, 4) void node_reduce_head(
    const float* __restrict__ msg_s,
    const int*   __restrict__ offs,
    const int*   __restrict__ batch,
    const float* __restrict__ W1,
    const float* __restrict__ b1,
    float*       __restrict__ g)           // [N_GRAPHS][20] (pre-zeroed)
{
    const int n = blockIdx.x * 256 + threadIdx.x;
    if (n >= N_NODES) return;

    const int o0 = offs[n], o1 = offs[n + 1];
    float acc[D_MSG];
#pragma unroll
    for (int j = 0; j < D_MSG; ++j) acc[j] = 0.0f;

    for (int o = o0; o < o1; ++o) {
        const float4* pr = (const float4*)(msg_s + (size_t)o * MSG_STRIDE);
#pragma unroll
        for (int q = 0; q < 7; ++q) {
            const float4 v = pr[q];
            acc[4*q+0] += v.x; acc[4*q+1] += v.y;
            acc[4*q+2] += v.z; acc[4*q+3] += v.w;
        }
        const float2 v2 = ((const float2*)pr)[14];
        acc[28] += v2.x; acc[29] += v2.y;
    }

    float h[D_H1];
#pragma unroll
    for (int t = 0; t < D_H1; ++t) h[t] = b1[t];
#pragma unroll
    for (int j = 0; j < D_MSG; ++j) {
#pragma unroll
        for (int t = 0; t < D_H1; ++t) h[t] = fmaf(acc[j], W1[j * D_H1 + t], h[t]);
    }

    const int gi = batch[n];
    float* gr = g + (size_t)gi * D_H1;
#pragma unroll
    for (int t = 0; t < D_H1; ++t) {
        const float hv = fmaxf(h[t], 0.0f);
        if (hv > 0.0f) atomicAdd(gr + t, hv);
    }
}

// ---------------------------------------------------------------------------
// K6: per-graph head  out = relu(g @ W2 + b2) @ W3 + b3
// ---------------------------------------------------------------------------
__global__ __launch_bounds__(256) void graph_head_kernel(
    const float* __restrict__ g, const float* __restrict__ W2,
    const float* __restrict__ b2, const float* __restrict__ W3,
    const float* __restrict__ b3, float* __restrict__ out)
{
    const int i = blockIdx.x * 256 + threadIdx.x;
    if (i >= N_GRAPHS) return;

    float gv[D_H1];
    const float2* pg = (const float2*)(g + (size_t)i * D_H1);
#pragma unroll
    for (int j = 0; j < D_H1 / 2; ++j) {
        const float2 t = pg[j];
        gv[2*j] = t.x; gv[2*j+1] = t.y;
    }

    float h[D_H2];
#pragma unroll
    for (int t = 0; t < D_H2; ++t) h[t] = b2[t];
#pragma unroll
    for (int j = 0; j < D_H1; ++j) {
#pragma unroll
        for (int t = 0; t < D_H2; ++t) h[t] = fmaf(gv[j], W2[j * D_H2 + t], h[t]);
    }

    float o = b3[0];
#pragma unroll
    for (int t = 0; t < D_H2; ++t) o = fmaf(fmaxf(h[t], 0.0f), W3[t], o);

    out[i] = o;
}

// ---------------------------------------------------------------------------
// Fallback (small ws): R2-style atomic accumulation into x[N_NODES][32].
// ---------------------------------------------------------------------------
__global__ __launch_bounds__(256, 4) void edge_msg_atomic(
    const int*   __restrict__ edge_index,
    const float* __restrict__ P,
    const float* __restrict__ edge_attr,
    const float* __restrict__ W_msg,
    float*       __restrict__ x)           // [N_NODES][32] (pre-zeroed)
{
    const int e = blockIdx.x * 256 + threadIdx.x;
    const int s = edge_index[e];
    const int d = edge_index[N_EDGES + e];

    const float4* p0 = (const float4*)(P + (size_t)s * P_STRIDE);
    const float4* p1 = (const float4*)(P + (size_t)d * P_STRIDE + 32);

    float acc[D_MSG];
#pragma unroll
    for (int q = 0; q < 7; ++q) {
        const float4 u = p0[q], w = p1[q];
        acc[4*q+0] = u.x + w.x; acc[4*q+1] = u.y + w.y;
        acc[4*q+2] = u.z + w.z; acc[4*q+3] = u.w + w.w;
    }
    {
        const float2 u = ((const float2*)p0)[14], w = ((const float2*)p1)[14];
        acc[28] = u.x + w.x; acc[29] = u.y + w.y;
    }

    const float* W2 = W_msg + 2 * D_FEAT * D_MSG;
    const float4* pe = (const float4*)(edge_attr + (size_t)e * D_FEAT);
#pragma unroll 2
    for (int q = 0; q < 16; ++q) {
        const float4 v  = pe[q];
        const float* wr = W2 + q * 4 * D_MSG;
#pragma unroll
        for (int j = 0; j < D_MSG; ++j) acc[j] = fmaf(v.x, wr[j],           acc[j]);
#pragma unroll
        for (int j = 0; j < D_MSG; ++j) acc[j] = fmaf(v.y, wr[D_MSG + j],   acc[j]);
#pragma unroll
        for (int j = 0; j < D_MSG; ++j) acc[j] = fmaf(v.z, wr[2*D_MSG + j], acc[j]);
#pragma unroll
        for (int j = 0; j < D_MSG; ++j) acc[j] = fmaf(v.w, wr[3*D_MSG + j], acc[j]);
    }

    float* xr = x + (size_t)d * 32;
#pragma unroll
    for (int j = 0; j < D_MSG; ++j) {
        const float m = fmaxf(acc[j], 0.0f);
        if (m > 0.0f) atomicAdd(xr + j, m);
    }
}

__global__ __launch_bounds__(256, 4) void node_head_direct(
    const float* __restrict__ x,        // [N_NODES][32]
    const int*   __restrict__ batch,
    const float* __restrict__ W1,
    const float* __restrict__ b1,
    float*       __restrict__ g)
{
    const int n = blockIdx.x * 256 + threadIdx.x;
    if (n >= N_NODES) return;

    float acc[D_MSG];
    const float4* pr = (const float4*)(x + (size_t)n * 32);
#pragma unroll
    for (int q = 0; q < 7; ++q) {
        const float4 v = pr[q];
        acc[4*q+0] = v.x; acc[4*q+1] = v.y; acc[4*q+2] = v.z; acc[4*q+3] = v.w;
    }
    const float2 v2 = ((const float2*)pr)[14];
    acc[28] = v2.x; acc[29] = v2.y;

    float h[D_H1];
#pragma unroll
    for (int t = 0; t < D_H1; ++t) h[t] = b1[t];
#pragma unroll
    for (int j = 0; j < D_MSG; ++j) {
#pragma unroll
        for (int t = 0; t < D_H1; ++t) h[t] = fmaf(acc[j], W1[j * D_H1 + t], h[t]);
    }

    const int gi = batch[n];
    float* gr = g + (size_t)gi * D_H1;
#pragma unroll
    for (int t = 0; t < D_H1; ++t) {
        const float hv = fmaxf(h[t], 0.0f);
        if (hv > 0.0f) atomicAdd(gr + t, hv);
    }
}

// ---------------------------------------------------------------------------
extern "C" void kernel_launch(void* const* d_in, const int* in_sizes, int n_in,
                              void* d_out, int out_size, void* d_ws, size_t ws_size,
                              hipStream_t stream)
{
    (void)in_sizes; (void)n_in; (void)out_size;

    const int*   edge_index = (const int*)  d_in[0];
    const float* node_attr  = (const float*)d_in[1];
    const float* edge_attr  = (const float*)d_in[2];
    const int*   batch      = (const int*)  d_in[3];
    const float* W_msg      = (const float*)d_in[4];
    const float* b_msg      = (const float*)d_in[5];
    const float* W1         = (const float*)d_in[6];
    const float* b1         = (const float*)d_in[7];
    const float* W2         = (const float*)d_in[8];
    const float* b2         = (const float*)d_in[9];
    const float* W3         = (const float*)d_in[10];
    const float* b3         = (const float*)d_in[11];

    // ws layout (main path):
    // P[N_NODES*64] | g[20000] | cnt[100004] | offs[100004] | cur[100004]
    // | bsum[128] | msg_s[N_EDGES*32]
    float* P    = (float*)d_ws;
    float* g    = P + (size_t)N_NODES * P_STRIDE;
    int*   cnt  = (int*)(g + (size_t)N_GRAPHS * D_H1);
    int*   offs = cnt + N_SCAN_PAD;
    int*   cur  = offs + N_SCAN_PAD;
    int*   bsum = cur + N_SCAN_PAD;
    float* msg_s = (float*)(bsum + 128);

    const size_t ws_need_main =
        ((size_t)N_NODES * P_STRIDE + (size_t)N_GRAPHS * D_H1) * 4 +
        ((size_t)3 * N_SCAN_PAD + 128) * 4 +
        (size_t)N_EDGES * MSG_STRIDE * 4;

    if (ws_size >= ws_need_main) {
        // zero g + cnt (adjacent)
        hipMemsetAsync(g, 0, ((size_t)N_GRAPHS * D_H1 + N_SCAN_PAD) * 4, stream);

        node_proj_kernel<<<(N_NODES + 255) / 256, 256, 0, stream>>>(
            node_attr, W_msg, b_msg, P);
        hist_kernel<<<N_EDGES / 256, 256, 0, stream>>>(edge_index, cnt);
        scan_a<<<NB_SCAN, 1024, 0, stream>>>(cnt, offs, bsum);
        scan_b<<<1, 128, 0, stream>>>(bsum);
        scan_c<<<NB_SCAN, 1024, 0, stream>>>(offs, bsum, cur);
        edge_msg_scatter<<<N_EDGES / 256, 256, 0, stream>>>(
            edge_index, P, edge_attr, W_msg, cur, msg_s);
        node_reduce_head<<<(N_NODES + 255) / 256, 256, 0, stream>>>(
            msg_s, offs, batch, W1, b1, g);
        graph_head_kernel<<<(N_GRAPHS + 255) / 256, 256, 0, stream>>>(
            g, W2, b2, W3, b3, (float*)d_out);
    } else {
        // fallback: P | g | x[N_NODES*32]
        float* x = g + (size_t)N_GRAPHS * D_H1;
        hipMemsetAsync(g, 0,
            ((size_t)N_GRAPHS * D_H1 + (size_t)N_NODES * 32) * 4, stream);

        node_proj_kernel<<<(N_NODES + 255) / 256, 256, 0, stream>>>(
            node_attr, W_msg, b_msg, P);
        edge_msg_atomic<<<N_EDGES / 256, 256, 0, stream>>>(
            edge_index, P, edge_attr, W_msg, x);
        node_head_direct<<<(N_NODES + 255) / 256, 256, 0, stream>>>(
            x, batch, W1, b1, g);
        graph_head_kernel<<<(N_GRAPHS + 255) / 256, 256, 0, stream>>>(
            g, W2, b2, W3, b3, (float*)d_out);
    }
}

// Round 4
// 532.766 us; speedup vs baseline: 3.8469x; 1.1384x over previous
//
#include <hip/hip_runtime.h>

#define N_NODES    100000
#define N_EDGES    1600000
#define D_FEAT     64
#define N_GRAPHS   1000
#define D_MSG      30
#define D_H1       20
#define D_H2       10
#define P_STRIDE   64     // P row: [0..29]=P0(src proj + bias), pad, [32..61]=P1(dst proj), pad
#define N_SCAN     (N_NODES + 1)
#define N_SCAN_PAD 100004
#define NB_SCAN    ((N_SCAN + 1023) / 1024)   // 98

// ---------------------------------------------------------------------------
// K0: per-node projections  P0[n] = x[n]@W0 + b_msg,  P1[n] = x[n]@W1
// W0|W1 (rows 0..127 of W_msg) staged in LDS, padded to stride 32 -> all
// weight reads are uniform-address LDS broadcasts (no per-lane W traffic).
// ---------------------------------------------------------------------------
__global__ __launch_bounds__(256, 4) void node_proj_kernel(
    const float* __restrict__ node_attr,   // [N_NODES][64]
    const float* __restrict__ W_msg,       // [192][30]
    const float* __restrict__ b_msg,       // [30]
    float*       __restrict__ P)           // [N_NODES][P_STRIDE]
{
    __shared__ float wlds[128 * 32];
    const int t = threadIdx.x;
#pragma unroll
    for (int i = 0; i < 16; ++i) {
        const int f = t + i * 256;          // 0..4095
        const int k = f >> 5, j = f & 31;
        wlds[f] = (j < D_MSG) ? W_msg[k * D_MSG + j] : 0.0f;
    }
    __syncthreads();

    const int n = blockIdx.x * 256 + t;
    if (n >= N_NODES) return;

    float a0[32], a1[32];
#pragma unroll
    for (int j = 0; j < 32; ++j) { a0[j] = 0.0f; a1[j] = 0.0f; }

    const float4* px = (const float4*)(node_attr + (size_t)n * D_FEAT);
#pragma unroll 4
    for (int q = 0; q < 16; ++q) {
        const float4 v = px[q];
        const float ev[4] = { v.x, v.y, v.z, v.w };
#pragma unroll
        for (int r = 0; r < 4; ++r) {
            const int k = 4 * q + r;
            const float4* w0 = (const float4*)&wlds[k * 32];
            const float4* w1 = (const float4*)&wlds[(64 + k) * 32];
#pragma unroll
            for (int jq = 0; jq < 8; ++jq) {
                const float4 w0v = w0[jq];
                const float4 w1v = w1[jq];
                a0[4*jq+0] = fmaf(ev[r], w0v.x, a0[4*jq+0]);
                a0[4*jq+1] = fmaf(ev[r], w0v.y, a0[4*jq+1]);
                a0[4*jq+2] = fmaf(ev[r], w0v.z, a0[4*jq+2]);
                a0[4*jq+3] = fmaf(ev[r], w0v.w, a0[4*jq+3]);
                a1[4*jq+0] = fmaf(ev[r], w1v.x, a1[4*jq+0]);
                a1[4*jq+1] = fmaf(ev[r], w1v.y, a1[4*jq+1]);
                a1[4*jq+2] = fmaf(ev[r], w1v.z, a1[4*jq+2]);
                a1[4*jq+3] = fmaf(ev[r], w1v.w, a1[4*jq+3]);
            }
        }
    }

    float4* pr = (float4*)(P + (size_t)n * P_STRIDE);
#pragma unroll
    for (int q = 0; q < 7; ++q)
        pr[q] = make_float4(a0[4*q] + b_msg[4*q], a0[4*q+1] + b_msg[4*q+1],
                            a0[4*q+2] + b_msg[4*q+2], a0[4*q+3] + b_msg[4*q+3]);
    pr[7] = make_float4(a0[28] + b_msg[28], a0[29] + b_msg[29], 0.0f, 0.0f);
#pragma unroll
    for (int q = 0; q < 7; ++q)
        pr[8 + q] = make_float4(a1[4*q], a1[4*q+1], a1[4*q+2], a1[4*q+3]);
    pr[15] = make_float4(a1[28], a1[29], 0.0f, 0.0f);
}

// ---------------------------------------------------------------------------
// CSR build: histogram of dst, 2-level exclusive scan, cursor init.
// ---------------------------------------------------------------------------
__global__ __launch_bounds__(256) void hist_kernel(
    const int* __restrict__ edge_index, int* __restrict__ cnt)
{
    const int e = blockIdx.x * 256 + threadIdx.x;
    atomicAdd(&cnt[edge_index[N_EDGES + e]], 1);
}

__global__ __launch_bounds__(1024) void scan_a(
    const int* __restrict__ cnt, int* __restrict__ offs, int* __restrict__ bsum)
{
    __shared__ int sh[1024];
    const int t = threadIdx.x;
    const int i = blockIdx.x * 1024 + t;
    const int v = (i < N_SCAN) ? cnt[i] : 0;
    sh[t] = v;
    __syncthreads();
#pragma unroll
    for (int off = 1; off < 1024; off <<= 1) {
        int u = 0;
        if (t >= off) u = sh[t - off];
        __syncthreads();
        if (t >= off) sh[t] += u;
        __syncthreads();
    }
    if (i < N_SCAN) offs[i] = sh[t] - v;
    if (t == 1023) bsum[blockIdx.x] = sh[1023];
}

__global__ __launch_bounds__(128) void scan_b(int* __restrict__ bsum)
{
    __shared__ int sh[128];
    const int t = threadIdx.x;
    const int v = (t < NB_SCAN) ? bsum[t] : 0;
    sh[t] = v;
    __syncthreads();
#pragma unroll
    for (int off = 1; off < 128; off <<= 1) {
        int u = 0;
        if (t >= off) u = sh[t - off];
        __syncthreads();
        if (t >= off) sh[t] += u;
        __syncthreads();
    }
    if (t < NB_SCAN) bsum[t] = sh[t] - v;
}

__global__ __launch_bounds__(1024) void scan_c(
    int* __restrict__ offs, const int* __restrict__ bsum, int* __restrict__ cur)
{
    const int i = blockIdx.x * 1024 + threadIdx.x;
    if (i < N_SCAN) {
        const int o = offs[i] + bsum[blockIdx.x];
        offs[i] = o;
        cur[i]  = o;
    }
}

// ---------------------------------------------------------------------------
// K4: scatter slot records (edge_id, src) into dst-sorted CSR order. 8B/edge.
// ---------------------------------------------------------------------------
__global__ __launch_bounds__(256) void scatter_rec(
    const int* __restrict__ edge_index, int* __restrict__ cur,
    int2* __restrict__ rec)
{
    const int e = blockIdx.x * 256 + threadIdx.x;
    const int s = edge_index[e];
    const int d = edge_index[N_EDGES + e];
    const int p = atomicAdd(&cur[d], 1);
    rec[p] = make_int2(e, s);
}

// ---------------------------------------------------------------------------
// K5: FUSED per-node kernel. 16 lanes per node (4 nodes/wave, 16 nodes/block).
// Each lane computes full messages for its slots:
//   m = P0[src] + P1[n] + e_attr[e] @ W2 ; acc += relu(m)
// then a 4-step shfl_xor butterfly gives all 16 lanes the node sum, and the
// lanes apply the 30->20 head and pool into g with skip-guarded atomics.
// Messages never touch memory. W2 staged in LDS (uniform broadcast reads).
// ---------------------------------------------------------------------------
__global__ __launch_bounds__(256, 4) void fused_edge_reduce_head(
    const int2*  __restrict__ rec,         // [N_EDGES] (e, src) dst-sorted
    const int*   __restrict__ offs,        // [N_NODES+1]
    const float* __restrict__ P,           // [N_NODES][P_STRIDE]
    const float* __restrict__ edge_attr,   // [N_EDGES][64]
    const float* __restrict__ W_msg,       // rows 128..191 = W2
    const int*   __restrict__ batch,       // [N_NODES]
    const float* __restrict__ W1,          // [30][20]
    const float* __restrict__ b1,          // [20]
    float*       __restrict__ g)           // [N_GRAPHS][20] (pre-zeroed)
{
    __shared__ float wlds[64 * 32];
    const int t = threadIdx.x;
#pragma unroll
    for (int i = 0; i < 8; ++i) {
        const int f = t + i * 256;          // 0..2047
        const int k = f >> 5, j = f & 31;
        wlds[f] = (j < D_MSG) ? W_msg[(2 * D_FEAT + k) * D_MSG + j] : 0.0f;
    }
    __syncthreads();

    const int lane = t & 63;
    const int l16  = lane & 15;
    const int grp  = lane >> 4;                       // 0..3
    const int wid  = t >> 6;                          // 0..3
    const int n    = blockIdx.x * 16 + wid * 4 + grp; // grid covers exactly N_NODES

    const int o0 = offs[n], o1 = offs[n + 1];
    const float4* p1 = (const float4*)(P + (size_t)n * P_STRIDE + 32);

    float acc[30];
#pragma unroll
    for (int j = 0; j < 30; ++j) acc[j] = 0.0f;

    for (int o = o0 + l16; o < o1; o += 16) {
        const int2 r2 = rec[o];
        const int e = r2.x, s = r2.y;
        const float4* p0 = (const float4*)(P + (size_t)s * P_STRIDE);
        const float4* pe = (const float4*)(edge_attr + (size_t)e * D_FEAT);

        float m[32];
#pragma unroll
        for (int q = 0; q < 8; ++q) {
            const float4 u = p0[q];
            const float4 w = p1[q];
            m[4*q+0] = u.x + w.x; m[4*q+1] = u.y + w.y;
            m[4*q+2] = u.z + w.z; m[4*q+3] = u.w + w.w;
        }
#pragma unroll 4
        for (int q = 0; q < 16; ++q) {
            const float4 v = pe[q];
            const float ev[4] = { v.x, v.y, v.z, v.w };
#pragma unroll
            for (int r = 0; r < 4; ++r) {
                const float4* wr = (const float4*)&wlds[(4 * q + r) * 32];
#pragma unroll
                for (int jq = 0; jq < 8; ++jq) {
                    const float4 wv = wr[jq];
                    m[4*jq+0] = fmaf(ev[r], wv.x, m[4*jq+0]);
                    m[4*jq+1] = fmaf(ev[r], wv.y, m[4*jq+1]);
                    m[4*jq+2] = fmaf(ev[r], wv.z, m[4*jq+2]);
                    m[4*jq+3] = fmaf(ev[r], wv.w, m[4*jq+3]);
                }
            }
        }
#pragma unroll
        for (int j = 0; j < 30; ++j) acc[j] += fmaxf(m[j], 0.0f);
    }

    // 16-lane butterfly: all lanes end with the full node sum
#pragma unroll
    for (int off = 1; off < 16; off <<= 1) {
#pragma unroll
        for (int j = 0; j < 30; ++j)
            acc[j] += __shfl_xor(acc[j], off, 16);
    }

    // head: output l16 on each lane; outputs 16..19 on lanes 0..3
    const int gi = batch[n];
    {
        float h = b1[l16];
#pragma unroll
        for (int j = 0; j < 30; ++j) h = fmaf(acc[j], W1[j * D_H1 + l16], h);
        h = fmaxf(h, 0.0f);
        if (h > 0.0f) atomicAdd(&g[(size_t)gi * D_H1 + l16], h);
    }
    if (l16 < 4) {
        const int t2 = 16 + l16;
        float h = b1[t2];
#pragma unroll
        for (int j = 0; j < 30; ++j) h = fmaf(acc[j], W1[j * D_H1 + t2], h);
        h = fmaxf(h, 0.0f);
        if (h > 0.0f) atomicAdd(&g[(size_t)gi * D_H1 + t2], h);
    }
}

// ---------------------------------------------------------------------------
// K6: per-graph head  out = relu(g @ W2 + b2) @ W3 + b3
// ---------------------------------------------------------------------------
__global__ __launch_bounds__(256) void graph_head_kernel(
    const float* __restrict__ g, const float* __restrict__ W2,
    const float* __restrict__ b2, const float* __restrict__ W3,
    const float* __restrict__ b3, float* __restrict__ out)
{
    const int i = blockIdx.x * 256 + threadIdx.x;
    if (i >= N_GRAPHS) return;

    float gv[D_H1];
    const float2* pg = (const float2*)(g + (size_t)i * D_H1);
#pragma unroll
    for (int j = 0; j < D_H1 / 2; ++j) {
        const float2 v = pg[j];
        gv[2*j] = v.x; gv[2*j+1] = v.y;
    }

    float h[D_H2];
#pragma unroll
    for (int tt = 0; tt < D_H2; ++tt) h[tt] = b2[tt];
#pragma unroll
    for (int j = 0; j < D_H1; ++j) {
#pragma unroll
        for (int tt = 0; tt < D_H2; ++tt) h[tt] = fmaf(gv[j], W2[j * D_H2 + tt], h[tt]);
    }

    float o = b3[0];
#pragma unroll
    for (int tt = 0; tt < D_H2; ++tt) o = fmaf(fmaxf(h[tt], 0.0f), W3[tt], o);

    out[i] = o;
}

// ---------------------------------------------------------------------------
extern "C" void kernel_launch(void* const* d_in, const int* in_sizes, int n_in,
                              void* d_out, int out_size, void* d_ws, size_t ws_size,
                              hipStream_t stream)
{
    (void)in_sizes; (void)n_in; (void)out_size; (void)ws_size;

    const int*   edge_index = (const int*)  d_in[0];
    const float* node_attr  = (const float*)d_in[1];
    const float* edge_attr  = (const float*)d_in[2];
    const int*   batch      = (const int*)  d_in[3];
    const float* W_msg      = (const float*)d_in[4];
    const float* b_msg      = (const float*)d_in[5];
    const float* W1         = (const float*)d_in[6];
    const float* b1         = (const float*)d_in[7];
    const float* W2         = (const float*)d_in[8];
    const float* b2         = (const float*)d_in[9];
    const float* W3         = (const float*)d_in[10];
    const float* b3         = (const float*)d_in[11];

    // ws: P[N_NODES*64] | g[20000] | cnt[100004] | offs[100004] | cur[100004]
    //     | bsum[128] | rec[N_EDGES int2]
    float* P    = (float*)d_ws;
    float* g    = P + (size_t)N_NODES * P_STRIDE;
    int*   cnt  = (int*)(g + (size_t)N_GRAPHS * D_H1);
    int*   offs = cnt + N_SCAN_PAD;
    int*   cur  = offs + N_SCAN_PAD;
    int*   bsum = cur + N_SCAN_PAD;
    int2*  rec  = (int2*)(bsum + 128);

    // zero g + cnt (adjacent)
    hipMemsetAsync(g, 0, ((size_t)N_GRAPHS * D_H1 + N_SCAN_PAD) * 4, stream);

    node_proj_kernel<<<(N_NODES + 255) / 256, 256, 0, stream>>>(
        node_attr, W_msg, b_msg, P);

    hist_kernel<<<N_EDGES / 256, 256, 0, stream>>>(edge_index, cnt);
    scan_a<<<NB_SCAN, 1024, 0, stream>>>(cnt, offs, bsum);
    scan_b<<<1, 128, 0, stream>>>(bsum);
    scan_c<<<NB_SCAN, 1024, 0, stream>>>(offs, bsum, cur);

    scatter_rec<<<N_EDGES / 256, 256, 0, stream>>>(edge_index, cur, rec);

    fused_edge_reduce_head<<<N_NODES / 16, 256, 0, stream>>>(
        rec, offs, P, edge_attr, W_msg, batch, W1, b1, g);

    graph_head_kernel<<<(N_GRAPHS + 255) / 256, 256, 0, stream>>>(
        g, W2, b2, W3, b3, (float*)d_out);
}